// Round 7
// baseline (117.018 us; speedup 1.0000x reference)
//
#include <hip/hip_runtime.h>
#include <math.h>

#define TWO_N 512
#define DM    256
#define NT    256

// ws layout: bsums [512] double @ 0
// One block per row i; no inter-block communication, no global R matrix.
__global__ __launch_bounds__(NT) void supcr_fused(
    const float* __restrict__ E, const float* __restrict__ T,
    double* __restrict__ bsums)
{
    const int i    = blockIdx.x;
    const int t    = threadIdx.x;
    const int lane = t & 63;
    const int wv   = t >> 6;            // wave 0..3

    __shared__ float  tv[TWO_N];        // targets, original order
    __shared__ float  ts[TWO_N];        // targets sorted ascending (stable)
    __shared__ int    inv_s[TWO_N];     // original idx -> sorted pos
    __shared__ float  rv[TWO_N];        // r[i,j], original order
    __shared__ float  P[TWO_N];         // s~ in sorted order -> prefix sums
    __shared__ double red[NT];
    __shared__ int    mi_s;

    tv[t]       = T[t];
    tv[t + 256] = T[t + 256];

    // e_i fragment in registers: lane l holds dims 4l..4l+3 (same in all waves)
    const float4* __restrict__ E4 = reinterpret_cast<const float4*>(E);
    const float4 ei4 = E4[i * 64 + lane];

    __syncthreads();

    const float ti = tv[i];

    // ---- rank-count sort of targets (2 cols/thread), bit-stable ties ----
    #pragma unroll
    for (int w = 0; w < 2; ++w) {
        const int c  = t + w * 256;
        const float tc = tv[c];
        int r = 0;
        #pragma unroll 8
        for (int j = 0; j < TWO_N; ++j) {
            const float tj = tv[j];      // LDS broadcast (wave-uniform j)
            r += (tj < tc) || (tj == tc && j < c);
        }
        ts[r]    = tc;
        inv_s[c] = r;
        if (c == i) mi_s = r;
    }
    __syncthreads();

    // ---- distance row: wave wv owns j in [128*wv, 128*wv+128), 4-way ILP ----
    for (int jj = 0; jj < 128; jj += 4) {
        const int j0 = (wv << 7) + jj;
        const float4 b0 = E4[((j0 + 0) << 6) + lane];   // coalesced 1KB/row
        const float4 b1 = E4[((j0 + 1) << 6) + lane];
        const float4 b2 = E4[((j0 + 2) << 6) + lane];
        const float4 b3 = E4[((j0 + 3) << 6) + lane];
        float v0, v1, v2, v3;
        {
            float dx, dy, dz, dw;
            dx = ei4.x - b0.x; dy = ei4.y - b0.y; dz = ei4.z - b0.z; dw = ei4.w - b0.w;
            v0 = dx * dx + dy * dy + dz * dz + dw * dw;
            dx = ei4.x - b1.x; dy = ei4.y - b1.y; dz = ei4.z - b1.z; dw = ei4.w - b1.w;
            v1 = dx * dx + dy * dy + dz * dz + dw * dw;
            dx = ei4.x - b2.x; dy = ei4.y - b2.y; dz = ei4.z - b2.z; dw = ei4.w - b2.w;
            v2 = dx * dx + dy * dy + dz * dz + dw * dw;
            dx = ei4.x - b3.x; dy = ei4.y - b3.y; dz = ei4.z - b3.z; dw = ei4.w - b3.w;
            v3 = dx * dx + dy * dy + dz * dz + dw * dw;
        }
        #pragma unroll
        for (int m = 1; m < 64; m <<= 1) {   // interleaved butterflies
            v0 += __shfl_xor(v0, m, 64);
            v1 += __shfl_xor(v1, m, 64);
            v2 += __shfl_xor(v2, m, 64);
            v3 += __shfl_xor(v3, m, 64);
        }
        if (lane == 0) {
            const float r0 = sqrtf(v0), r1 = sqrtf(v1);
            const float r2 = sqrtf(v2), r3 = sqrtf(v3);
            rv[j0 + 0] = r0;
            rv[j0 + 1] = r1;
            rv[j0 + 2] = r2;
            rv[j0 + 3] = r3;
            P[inv_s[j0 + 0]] = (j0 + 0 == i) ? 0.f : __expf(-r0);
            P[inv_s[j0 + 1]] = (j0 + 1 == i) ? 0.f : __expf(-r1);
            P[inv_s[j0 + 2]] = (j0 + 2 == i) ? 0.f : __expf(-r2);
            P[inv_s[j0 + 3]] = (j0 + 3 == i) ? 0.f : __expf(-r3);
        }
    }
    __syncthreads();

    // ---- inclusive prefix sum of P (Hillis-Steele, 2 elems/thread) ----
    for (int off = 1; off < TWO_N; off <<= 1) {
        const float v0 = (t >= off)       ? P[t - off]       : 0.f;
        const float v1 = (t + 256 >= off) ? P[t + 256 - off] : 0.f;
        __syncthreads();
        P[t]       += v0;
        P[t + 256] += v1;
        __syncthreads();
    }

    const float Stot = P[TWO_N - 1];
    const int   mi   = mi_s;

    // ---- per-k monotone searches -> contiguous {d < theta} interval ----
    float local = 0.f;
    #pragma unroll
    for (int w = 0; w < 2; ++w) {
        const int k = t + w * 256;       // original index
        if (k == i) continue;
        const float theta = fabsf(ti - tv[k]);

        // left arm [0, mi]: d non-increasing; count leading d >= theta
        const int nl = mi + 1;
        int pos = 0;
        #pragma unroll
        for (int step = 512; step >= 1; step >>= 1) {
            const int np = pos + step;
            if (np <= nl && fabsf(ti - ts[np - 1]) >= theta) pos = np;
        }
        const int cl = nl - pos;         // left-arm count with d < theta

        // right arm [mi, 511]: d non-decreasing; count leading d < theta
        const int nr = TWO_N - mi;
        int pr = 0;
        #pragma unroll
        for (int step = 512; step >= 1; step >>= 1) {
            const int np = pr + step;
            if (np <= nr && fabsf(ti - ts[mi + np - 1]) < theta) pr = np;
        }

        const int L  = mi - cl + 1;
        const int Rr = mi + pr - 1;
        float inner = 0.f;
        if (Rr >= L) inner = P[Rr] - ((L > 0) ? P[L - 1] : 0.f);
        const float denom = Stot - inner;   // = sum over {d >= theta, j != i}
        local += -rv[k] - logf(denom);
    }

    // ---- block reduction (double), plain store ----
    red[t] = (double)local;
    __syncthreads();
    for (int off = NT / 2; off > 0; off >>= 1) {
        if (t < off) red[t] += red[t + off];
        __syncthreads();
    }
    if (t == 0) bsums[i] = red[0];
}

__global__ __launch_bounds__(TWO_N) void supcr_finalize(
    const double* __restrict__ bsums, float* __restrict__ out)
{
    __shared__ double red[TWO_N];
    const int t = threadIdx.x;
    red[t] = bsums[t];
    __syncthreads();
    for (int off = TWO_N / 2; off > 0; off >>= 1) {
        if (t < off) red[t] += red[t + off];
        __syncthreads();
    }
    if (t == 0)
        out[0] = (float)(-red[0] / (double)((long long)TWO_N * (TWO_N - 1)));
}

extern "C" void kernel_launch(void* const* d_in, const int* in_sizes, int n_in,
                              void* d_out, int out_size, void* d_ws, size_t ws_size,
                              hipStream_t stream) {
    (void)in_sizes; (void)n_in; (void)out_size; (void)ws_size;
    const float* E = (const float*)d_in[0];   // [512,256] fp32
    const float* T = (const float*)d_in[1];   // [512]     fp32
    float* out = (float*)d_out;
    double* bsums = (double*)d_ws;            // 4 KB of ws

    supcr_fused<<<TWO_N, NT, 0, stream>>>(E, T, bsums);
    supcr_finalize<<<1, TWO_N, 0, stream>>>(bsums, out);
}

// Round 8
// 85.901 us; speedup vs baseline: 1.3622x; 1.3622x over previous
//
#include <hip/hip_runtime.h>
#include <math.h>

#define TWO_N 512
#define DM    256
#define NT    256

// ws layout (bytes):
//   R     : [512*512] float @ 0         -- distances, natural (row, col) order
//   ts    : [512] float     @ 1048576   -- targets sorted ascending (stable)
//   perm  : [512] int       @ 1050624   -- perm[m] = original index at sorted pos m
//   inv   : [512] int       @ 1052672   -- inv[c]  = sorted position of target c
//   bsums : [512] double    @ 1054720
#define OFF_TS   1048576
#define OFF_PERM 1050624
#define OFF_INV  1052672
#define OFF_BSUM 1054720

#define ACC4(acc, A, B) { float _d;                      \
    _d = (A).x - (B).x; acc += _d * _d;                  \
    _d = (A).y - (B).y; acc += _d * _d;                  \
    _d = (A).z - (B).z; acc += _d * _d;                  \
    _d = (A).w - (B).w; acc += _d * _d; }

// Blocks 0..255: 32x32 distance tiles, coalesced reads AND writes.
// Block 256: rank-count sort of targets -> ts/perm/inv.
__global__ __launch_bounds__(NT) void supcr_dist_sort(
    const float* __restrict__ E, const float* __restrict__ T,
    float* __restrict__ R, float* __restrict__ ts_g,
    int* __restrict__ perm_g, int* __restrict__ inv_g)
{
    const int bid = blockIdx.x;
    const int t   = threadIdx.x;

    if (bid < 256) {
        __shared__ float4 As4[32 * 65];   // padded rows: bank-friendly
        __shared__ float4 Bs4[32 * 65];
        const int it = bid >> 4, jt = bid & 15;
        const float4* __restrict__ E4 = reinterpret_cast<const float4*>(E);

        for (int idx = t; idx < 32 * 64; idx += NT) {    // coalesced staging
            const int row = idx >> 6, c4 = idx & 63;
            As4[row * 65 + c4] = E4[(it * 32 + row) * 64 + c4];
            Bs4[row * 65 + c4] = E4[(jt * 32 + row) * 64 + c4];
        }
        __syncthreads();

        const int ty = t >> 4, tx = t & 15;
        float a00 = 0.f, a01 = 0.f, a10 = 0.f, a11 = 0.f;
        #pragma unroll 8
        for (int k4 = 0; k4 < 64; ++k4) {
            const float4 a0 = As4[ty * 65 + k4];
            const float4 a1 = As4[(ty + 16) * 65 + k4];
            const float4 b0 = Bs4[tx * 65 + k4];
            const float4 b1 = Bs4[(tx + 16) * 65 + k4];
            ACC4(a00, a0, b0); ACC4(a01, a0, b1);
            ACC4(a10, a1, b0); ACC4(a11, a1, b1);
        }
        const int r0 = it * 32 + ty, r1 = r0 + 16;
        const int c0 = jt * 32 + tx, c1 = c0 + 16;
        R[r0 * TWO_N + c0] = sqrtf(a00);
        R[r0 * TWO_N + c1] = sqrtf(a01);
        R[r1 * TWO_N + c0] = sqrtf(a10);
        R[r1 * TWO_N + c1] = sqrtf(a11);
    } else {
        // rank-count sort of 512 targets (2 elems/thread), bit-stable ties
        __shared__ float tv[TWO_N];
        tv[t]       = T[t];
        tv[t + 256] = T[t + 256];
        __syncthreads();
        #pragma unroll
        for (int w = 0; w < 2; ++w) {
            const int c  = t + w * 256;
            const float tc = tv[c];
            int r = 0;
            #pragma unroll 8
            for (int j = 0; j < TWO_N; ++j) {
                const float tj = tv[j];
                r += (tj < tc) || (tj == tc && j < c);
            }
            ts_g[r]   = tc;
            perm_g[r] = c;
            inv_g[c]  = r;
        }
    }
}

// One block per row i. Thread t owns sorted positions {2t, 2t+1}.
// Wave-level scan for prefix sums; 4 barriers total.
__global__ __launch_bounds__(NT) void supcr_rows(
    const float* __restrict__ T, const float* __restrict__ R,
    const float* __restrict__ ts_g, const int* __restrict__ perm_g,
    const int* __restrict__ inv_g, double* __restrict__ bsums)
{
    const int i    = blockIdx.x;
    const int t    = threadIdx.x;
    const int lane = t & 63;
    const int wv   = t >> 6;

    __shared__ float  ts[TWO_N];
    __shared__ float  P[TWO_N];       // inclusive prefix sums (sorted order)
    __shared__ float  wtot[4];
    __shared__ double dred[4];
    __shared__ int    mi_s;

    const int   m0 = 2 * t, m1 = 2 * t + 1;
    const float ti = T[i];
    const float* __restrict__ row = R + (size_t)i * TWO_N;

    // sorted keys + permutation (coalesced vector loads)
    const float2 tg = reinterpret_cast<const float2*>(ts_g)[t];
    const int2   pg = reinterpret_cast<const int2*>(perm_g)[t];
    ts[m0] = tg.x;
    ts[m1] = tg.y;

    // gather this thread's two distances (2KB row, L2/L3-resident)
    const float r0 = row[pg.x];
    const float r1 = row[pg.y];
    const float e0 = (pg.x == i) ? 0.f : __expf(-r0);
    const float e1 = (pg.y == i) ? 0.f : __expf(-r1);

    // wave-inclusive scan of pair sums (no barriers)
    float s = e0 + e1;
    #pragma unroll
    for (int off = 1; off < 64; off <<= 1) {
        const float n = __shfl_up(s, off, 64);
        if (lane >= off) s += n;
    }
    if (lane == 63) wtot[wv] = s;
    if (pg.x == i) mi_s = m0;
    if (pg.y == i) mi_s = m1;
    __syncthreads();                               // B1: wtot, mi_s, ts visible

    float woff = 0.f;
    #pragma unroll
    for (int w = 0; w < 3; ++w) woff += (w < wv) ? wtot[w] : 0.f;
    const float Stot = wtot[0] + wtot[1] + wtot[2] + wtot[3];

    const float excl = woff + s - (e0 + e1);       // exclusive before m0
    P[m0] = excl + e0;
    P[m1] = excl + e0 + e1;
    __syncthreads();                               // B2: P visible

    const int mi = mi_s;
    const int nl = mi + 1;
    const int nr = TWO_N - mi;

    float local = 0.f;
    #pragma unroll
    for (int w = 0; w < 2; ++w) {
        const int   m     = (w == 0) ? m0 : m1;
        const int   pj    = (w == 0) ? pg.x : pg.y;
        const float rm    = (w == 0) ? r0 : r1;
        if (pj == i) continue;
        const float theta = fabsf(ti - ts[m]);

        // left arm [0, mi]: d non-increasing; count leading d >= theta
        int pos = 0;
        #pragma unroll
        for (int step = 512; step >= 1; step >>= 1) {
            const int np = pos + step;
            if (np <= nl && fabsf(ti - ts[np - 1]) >= theta) pos = np;
        }
        const int cl = nl - pos;                   // left-arm count with d < theta

        // right arm [mi, 511]: d non-decreasing; count leading d < theta
        int pr = 0;
        #pragma unroll
        for (int step = 512; step >= 1; step >>= 1) {
            const int np = pr + step;
            if (np <= nr && fabsf(ti - ts[mi + np - 1]) < theta) pr = np;
        }

        const int L  = mi - cl + 1;
        const int Rr = mi + pr - 1;
        float inner = 0.f;
        if (Rr >= L) inner = P[Rr] - ((L > 0) ? P[L - 1] : 0.f);
        const float denom = Stot - inner;          // = sum over {d >= theta, j != i}
        local += -rm - __logf(denom);
    }

    // wave reduce (f32) -> per-wave double -> single-thread combine
    #pragma unroll
    for (int off = 32; off >= 1; off >>= 1)
        local += __shfl_down(local, off, 64);
    if (lane == 0) dred[wv] = (double)local;
    __syncthreads();                               // B3
    if (t == 0)
        bsums[i] = dred[0] + dred[1] + dred[2] + dred[3];
}

__global__ __launch_bounds__(TWO_N) void supcr_finalize(
    const double* __restrict__ bsums, float* __restrict__ out)
{
    __shared__ double part[8];
    const int t    = threadIdx.x;
    const int lane = t & 63;
    const int wv   = t >> 6;

    double v = bsums[t];
    #pragma unroll
    for (int off = 32; off >= 1; off >>= 1)
        v += __shfl_down(v, off, 64);
    if (lane == 0) part[wv] = v;
    __syncthreads();
    if (t == 0) {
        double s = 0.0;
        #pragma unroll
        for (int w = 0; w < 8; ++w) s += part[w];
        out[0] = (float)(-s / (double)((long long)TWO_N * (TWO_N - 1)));
    }
}

extern "C" void kernel_launch(void* const* d_in, const int* in_sizes, int n_in,
                              void* d_out, int out_size, void* d_ws, size_t ws_size,
                              hipStream_t stream) {
    (void)in_sizes; (void)n_in; (void)out_size; (void)ws_size;
    const float* E = (const float*)d_in[0];   // [512,256] fp32
    const float* T = (const float*)d_in[1];   // [512]     fp32
    float* out = (float*)d_out;

    char* ws = (char*)d_ws;
    float*  R      = (float*)(ws);
    float*  ts_g   = (float*)(ws + OFF_TS);
    int*    perm_g = (int*)(ws + OFF_PERM);
    int*    inv_g  = (int*)(ws + OFF_INV);
    double* bsums  = (double*)(ws + OFF_BSUM);

    supcr_dist_sort<<<257, NT, 0, stream>>>(E, T, R, ts_g, perm_g, inv_g);
    supcr_rows<<<TWO_N, NT, 0, stream>>>(T, R, ts_g, perm_g, inv_g, bsums);
    supcr_finalize<<<1, TWO_N, 0, stream>>>(bsums, out);
}